// Round 1
// baseline (1554.178 us; speedup 1.0000x reference)
//
#include <hip/hip_runtime.h>
#include <hip/hip_bf16.h>
#include <type_traits>

// ---------------------------------------------------------------------------
// PerceiverAttention on MI355X.
// Pipeline:
//   1) transpose_bf16 x3 : Wkv->WkvT, Wq->WqT, Wo->WoT  (bf16, [N][K] layout)
//   2) ln_kernel         : LayerNorm src+ltn -> ctx bf16 [66048][768]; ltn rows
//                          also compacted into qin bf16 [512][768]
//   3) gemm_bt<ushort>   : kv  = ctx @ WkvT^T   -> bf16 [66048][1024]
//   4) gemm_bt<float>    : q   = qin @ WqT^T    -> f32  [512][512]
//   5) attn_kernel       : online-softmax attention -> out_pre bf16 [512][512]
//   6) gemm_bt<float>    : out = out_pre @ WoT^T -> f32 d_out [512][768]
// ---------------------------------------------------------------------------

#define N_SRC 8192
#define N_LTN 64
#define N_CTX 8256            // per (b,t)
#define NBT 8                 // b*t
#define MROWS 66048           // NBT * N_CTX
#define DIMK 768
#define DEMB 512

typedef short short8 __attribute__((ext_vector_type(8)));
typedef float floatx4 __attribute__((ext_vector_type(4)));
typedef __attribute__((address_space(1))) void gvoid;
typedef __attribute__((address_space(3))) void lvoid;

__device__ inline ushort f2bf(float f) {
    union { float f; unsigned u; } v; v.f = f;
    unsigned u = v.u;
    return (ushort)((u + 0x7fffu + ((u >> 16) & 1u)) >> 16);   // RNE
}
__device__ inline float2 bfp2(unsigned u) {
    union { unsigned i; float f; } a, b;
    a.i = u << 16; b.i = u & 0xffff0000u;
    return make_float2(a.f, b.f);
}

// --------------------------- weight transpose ------------------------------
// in: fp32 [R][C]  ->  out: bf16 [C][R]
__global__ __launch_bounds__(256) void transpose_bf16(
        const float* __restrict__ in, ushort* __restrict__ out, int R, int C) {
    int gid = blockIdx.x * 256 + threadIdx.x;
    if (gid >= R * C) return;
    int c = gid / R, r = gid - c * R;
    out[gid] = f2bf(in[(size_t)r * C + c]);
}

// ------------------------------ layernorm ----------------------------------
// one wave per row; 4 rows per 256-thread block
__global__ __launch_bounds__(256) void ln_kernel(
        const float* __restrict__ src, const float* __restrict__ ltn,
        const float* __restrict__ gs, const float* __restrict__ bs,
        const float* __restrict__ gl, const float* __restrict__ bl,
        ushort* __restrict__ ctx, ushort* __restrict__ qin) {
    int r = blockIdx.x * 4 + (threadIdx.x >> 6);
    int lane = threadIdx.x & 63;
    int bt = r / N_CTX;
    int i = r - bt * N_CTX;
    const float *x, *g, *b;
    int isl = (i >= N_SRC);
    if (!isl) { x = src + ((size_t)bt * N_SRC + i) * DIMK; g = gs; b = bs; }
    else      { x = ltn + ((size_t)bt * N_LTN + (i - N_SRC)) * DIMK; g = gl; b = bl; }
    float v[12]; float s = 0.f, s2 = 0.f;
#pragma unroll
    for (int t = 0; t < 12; t++) {
        float xv = x[lane + t * 64];
        v[t] = xv; s += xv; s2 += xv * xv;
    }
#pragma unroll
    for (int off = 32; off >= 1; off >>= 1) {
        s  += __shfl_xor(s,  off, 64);
        s2 += __shfl_xor(s2, off, 64);
    }
    float mu  = s * (1.0f / 768.0f);
    float var = s2 * (1.0f / 768.0f) - mu * mu;
    float rs  = rsqrtf(var + 1e-5f);
    ushort* crow = ctx + (size_t)r * DIMK;
    ushort* qrow = isl ? (qin + (size_t)(bt * N_LTN + (i - N_SRC)) * DIMK) : nullptr;
#pragma unroll
    for (int t = 0; t < 12; t++) {
        int idx = lane + t * 64;
        float y = (v[t] - mu) * rs * g[idx] + b[idx];
        ushort hb = f2bf(y);
        crow[idx] = hb;
        if (isl) qrow[idx] = hb;
    }
}

// ------------------------------- GEMM --------------------------------------
// C[M][N] = A[M][K] @ B[N][K]^T , A/B bf16, acc fp32.
// 128x128 tile, BK=64, 256 threads (4 waves, 2x2 of 64x64 per wave).
// global_load_lds(16B) staging with XOR chunk swizzle (conflict-free ds_read_b128).
template <typename CT>
__global__ __launch_bounds__(256) void gemm_bt(
        const ushort* __restrict__ A, const ushort* __restrict__ B,
        CT* __restrict__ C, int M, int N, int K) {
    __shared__ ushort lA[128 * 64];
    __shared__ ushort lB[128 * 64];
    int tid = threadIdx.x;
    int lane = tid & 63, wave = tid >> 6;
    int wm = wave >> 1, wn = wave & 1;
    int bm = blockIdx.x, bn = blockIdx.y;

    floatx4 acc[4][4];
#pragma unroll
    for (int mi = 0; mi < 4; mi++)
#pragma unroll
        for (int ni = 0; ni < 4; ni++) acc[mi][ni] = (floatx4){0.f, 0.f, 0.f, 0.f};

    int srow = lane >> 3;                 // 0..7 row within 8-row group
    int schunk = (lane & 7) ^ srow;       // swizzled 16B chunk index fetched
    int quad = lane >> 4, lr = lane & 15;
    const int kiters = K >> 6;

    for (int kt = 0; kt < kiters; kt++) {
        // stage A and B tiles: wave covers rows {c2*32 + wave*8 + 0..7}
#pragma unroll
        for (int c2 = 0; c2 < 4; c2++) {
            int row = c2 * 32 + wave * 8 + srow;
            const ushort* gpA = A + ((size_t)(bm * 128 + row) * K + kt * 64 + schunk * 8);
            ushort* lpA = lA + (c2 * 32 + wave * 8) * 64 + lane * 8;
            __builtin_amdgcn_global_load_lds((gvoid*)gpA, (lvoid*)lpA, 16, 0, 0);
            const ushort* gpB = B + ((size_t)(bn * 128 + row) * K + kt * 64 + schunk * 8);
            ushort* lpB = lB + (c2 * 32 + wave * 8) * 64 + lane * 8;
            __builtin_amdgcn_global_load_lds((gvoid*)gpB, (lvoid*)lpB, 16, 0, 0);
        }
        __syncthreads();
#pragma unroll
        for (int ks = 0; ks < 2; ks++) {
            short8 av[4], bv[4];
            int slot = ((ks * 4 + quad) ^ (lane & 7)) * 8;  // un-swizzle
#pragma unroll
            for (int mi = 0; mi < 4; mi++)
                av[mi] = *(const short8*)(lA + (wm * 64 + mi * 16 + lr) * 64 + slot);
#pragma unroll
            for (int ni = 0; ni < 4; ni++)
                bv[ni] = *(const short8*)(lB + (wn * 64 + ni * 16 + lr) * 64 + slot);
#pragma unroll
            for (int mi = 0; mi < 4; mi++)
#pragma unroll
                for (int ni = 0; ni < 4; ni++)
                    acc[mi][ni] = __builtin_amdgcn_mfma_f32_16x16x32_bf16(
                        av[mi], bv[ni], acc[mi][ni], 0, 0, 0);
        }
        __syncthreads();
    }
    // epilogue: C/D layout col=lane&15, row=quad*4+reg
#pragma unroll
    for (int mi = 0; mi < 4; mi++)
#pragma unroll
        for (int ni = 0; ni < 4; ni++)
#pragma unroll
            for (int r = 0; r < 4; r++) {
                int row = bm * 128 + wm * 64 + mi * 16 + quad * 4 + r;
                int col = bn * 128 + wn * 64 + ni * 16 + lr;
                float vv = acc[mi][ni][r];
                if constexpr (std::is_same<CT, ushort>::value)
                    C[(size_t)row * N + col] = f2bf(vv);
                else
                    C[(size_t)row * N + col] = vv;
            }
}

// ------------------------------ attention ----------------------------------
// one wave per (bt, h, query). Each lane runs online softmax over 129 keys,
// then LDS-transpose combine across the 64 lane-states.
__device__ inline void dot8(uint4 u, const float2* q4, float2& s2) {
    float2 f;
    f = bfp2(u.x); s2.x = fmaf(f.x, q4[0].x, s2.x); s2.y = fmaf(f.y, q4[0].y, s2.y);
    f = bfp2(u.y); s2.x = fmaf(f.x, q4[1].x, s2.x); s2.y = fmaf(f.y, q4[1].y, s2.y);
    f = bfp2(u.z); s2.x = fmaf(f.x, q4[2].x, s2.x); s2.y = fmaf(f.y, q4[2].y, s2.y);
    f = bfp2(u.w); s2.x = fmaf(f.x, q4[3].x, s2.x); s2.y = fmaf(f.y, q4[3].y, s2.y);
}
__device__ inline void acc8(uint4 u, float w, float2* a4) {
    float2 f;
    f = bfp2(u.x); a4[0].x = fmaf(w, f.x, a4[0].x); a4[0].y = fmaf(w, f.y, a4[0].y);
    f = bfp2(u.y); a4[1].x = fmaf(w, f.x, a4[1].x); a4[1].y = fmaf(w, f.y, a4[1].y);
    f = bfp2(u.z); a4[2].x = fmaf(w, f.x, a4[2].x); a4[2].y = fmaf(w, f.y, a4[2].y);
    f = bfp2(u.w); a4[3].x = fmaf(w, f.x, a4[3].x); a4[3].y = fmaf(w, f.y, a4[3].y);
}
__device__ inline void rescale8(uint4 u, float cc, float2* a4) {
    float2 f;
    f = bfp2(u.x); a4[0].x = fmaf(a4[0].x, cc, f.x); a4[0].y = fmaf(a4[0].y, cc, f.y);
    f = bfp2(u.y); a4[1].x = fmaf(a4[1].x, cc, f.x); a4[1].y = fmaf(a4[1].y, cc, f.y);
    f = bfp2(u.z); a4[2].x = fmaf(a4[2].x, cc, f.x); a4[2].y = fmaf(a4[2].y, cc, f.y);
    f = bfp2(u.w); a4[3].x = fmaf(a4[3].x, cc, f.x); a4[3].y = fmaf(a4[3].y, cc, f.y);
}

__global__ __launch_bounds__(64) void attn_kernel(
        const float* __restrict__ q, const ushort* __restrict__ kv,
        ushort* __restrict__ outp) {
    __shared__ float red[64 * 68];       // per-lane state: acc[64], m, l
    int gid = blockIdx.x;
    int bt = gid >> 9, h = (gid >> 6) & 7, qi = gid & 63;
    int lane = threadIdx.x;

    const float2* qr = (const float2*)(q + (size_t)(bt * 64 + qi) * DEMB + h * 64);
    float2 qv[32];
#pragma unroll
    for (int t = 0; t < 32; t++) qv[t] = qr[t];

    const ushort* kb = kv + (size_t)bt * N_CTX * 1024 + h * 64;
    const ushort* vb = kb + 512;

    float m = -1e30f, l = 0.f;
    float2 acc[32];
#pragma unroll
    for (int t = 0; t < 32; t++) acc[t] = make_float2(0.f, 0.f);

    for (int j = lane; j < N_CTX; j += 64) {
        const uint4* kp = (const uint4*)(kb + (size_t)j * 1024);
        float2 s2 = make_float2(0.f, 0.f);
        uint4 kk[8];
#pragma unroll
        for (int t4 = 0; t4 < 8; t4++) kk[t4] = kp[t4];
#pragma unroll
        for (int t4 = 0; t4 < 8; t4++) dot8(kk[t4], &qv[t4 * 4], s2);
        float s = (s2.x + s2.y) * 0.125f;

        const uint4* vp = (const uint4*)(vb + (size_t)j * 1024);
        uint4 vv[8];
#pragma unroll
        for (int t4 = 0; t4 < 8; t4++) vv[t4] = vp[t4];

        if (s <= m) {
            float w = __expf(s - m);
            l += w;
#pragma unroll
            for (int t4 = 0; t4 < 8; t4++) acc8(vv[t4], w, &acc[t4 * 4]);
        } else {
            float cc = __expf(m - s);
            m = s;
            l = fmaf(l, cc, 1.0f);
#pragma unroll
            for (int t4 = 0; t4 < 8; t4++) rescale8(vv[t4], cc, &acc[t4 * 4]);
        }
    }

    // combine 64 lane-states via LDS transpose
    float* myrow = red + lane * 68;
#pragma unroll
    for (int t = 0; t < 32; t++) { myrow[2 * t] = acc[t].x; myrow[2 * t + 1] = acc[t].y; }
    myrow[64] = m; myrow[65] = l;
    __syncthreads();

    float M = -1e30f;
    for (int w = 0; w < 64; w++) M = fmaxf(M, red[w * 68 + 64]);
    float L = 0.f, Aacc = 0.f;
    for (int w = 0; w < 64; w++) {
        float e = __expf(red[w * 68 + 64] - M);
        L    = fmaf(red[w * 68 + 65], e, L);
        Aacc = fmaf(red[w * 68 + lane], e, Aacc);
    }
    outp[(size_t)(bt * 64 + qi) * DEMB + h * 64 + lane] = f2bf(Aacc / L);
}

// ------------------------------ launcher -----------------------------------
extern "C" void kernel_launch(void* const* d_in, const int* in_sizes, int n_in,
                              void* d_out, int out_size, void* d_ws, size_t ws_size,
                              hipStream_t stream) {
    const float* src   = (const float*)d_in[0];
    const float* ltn   = (const float*)d_in[1];
    const float* g_src = (const float*)d_in[2];
    const float* b_src = (const float*)d_in[3];
    const float* g_ltn = (const float*)d_in[4];
    const float* b_ltn = (const float*)d_in[5];
    const float* Wq    = (const float*)d_in[6];
    const float* Wkv   = (const float*)d_in[7];
    const float* Wo    = (const float*)d_in[8];
    float* out = (float*)d_out;

    char* ws = (char*)d_ws;
    size_t off = 0;
    auto alloc = [&](size_t bytes) -> void* {
        void* p = ws + off;
        off += (bytes + 255) & ~(size_t)255;
        return p;
    };
    ushort* ctx  = (ushort*)alloc((size_t)MROWS * DIMK * 2);   // 101.4 MB
    ushort* qin  = (ushort*)alloc((size_t)512 * DIMK * 2);
    ushort* WkvT = (ushort*)alloc((size_t)1024 * DIMK * 2);
    ushort* WqT  = (ushort*)alloc((size_t)512 * DIMK * 2);
    ushort* WoT  = (ushort*)alloc((size_t)768 * DEMB * 2);
    ushort* kvb  = (ushort*)alloc((size_t)MROWS * 1024 * 2);   // 135.3 MB
    float*  qf   = (float*) alloc((size_t)512 * DEMB * 4);
    ushort* outp = (ushort*)alloc((size_t)512 * DEMB * 2);

    transpose_bf16<<<(768 * 1024 + 255) / 256, 256, 0, stream>>>(Wkv, WkvT, 768, 1024);
    transpose_bf16<<<(768 * 512 + 255) / 256, 256, 0, stream>>>(Wq, WqT, 768, 512);
    transpose_bf16<<<(512 * 768 + 255) / 256, 256, 0, stream>>>(Wo, WoT, 512, 768);

    ln_kernel<<<MROWS / 4, 256, 0, stream>>>(src, ltn, g_src, b_src, g_ltn, b_ltn, ctx, qin);

    gemm_bt<ushort><<<dim3(MROWS / 128, 1024 / 128), 256, 0, stream>>>(
        ctx, WkvT, kvb, MROWS, 1024, DIMK);
    gemm_bt<float><<<dim3(512 / 128, 512 / 128), 256, 0, stream>>>(
        qin, WqT, qf, 512, 512, DIMK);

    attn_kernel<<<4096, 64, 0, stream>>>(qf, kvb, outp);

    gemm_bt<float><<<dim3(512 / 128, 768 / 128), 256, 0, stream>>>(
        outp, WoT, out, 512, 768, DEMB);
}

// Round 2
// 583.398 us; speedup vs baseline: 2.6640x; 2.6640x over previous
//
#include <hip/hip_runtime.h>
#include <hip/hip_bf16.h>
#include <type_traits>

// ---------------------------------------------------------------------------
// PerceiverAttention on MI355X.
// Pipeline:
//   1) transpose_bf16 x3 : Wkv->WkvT, Wq->WqT, Wo->WoT  (bf16, [N][K] layout)
//   2) ln_kernel         : LayerNorm src+ltn -> ctx bf16 [66048][768]; ltn rows
//                          also compacted into qin bf16 [512][768]
//   3) gemm_bt<ushort>   : kv  = ctx @ WkvT^T   -> bf16 [66048][1024]
//   4) gemm_bt<float>    : q   = qin @ WqT^T    -> f32  [512][512]
//   5) attn_flash        : split-K MFMA flash attention -> partials (O~,m,l)
//      attn_combine      : merge 16 splits -> out_pre bf16 [512][512]
//   6) gemm_bt<float>    : out = out_pre @ WoT^T -> f32 d_out [512][768]
// ---------------------------------------------------------------------------

#define N_SRC 8192
#define N_LTN 64
#define N_CTX 8256            // per (b,t)
#define NBT 8                 // b*t
#define MROWS 66048           // NBT * N_CTX
#define DIMK 768
#define DEMB 512
#define NSPLIT 16
#define NTILES 65             // ceil(N_CTX / 128)

typedef short short8 __attribute__((ext_vector_type(8)));
typedef float floatx4 __attribute__((ext_vector_type(4)));
typedef __attribute__((address_space(1))) void gvoid;
typedef __attribute__((address_space(3))) void lvoid;

__device__ inline ushort f2bf(float f) {
    union { float f; unsigned u; } v; v.f = f;
    unsigned u = v.u;
    return (ushort)((u + 0x7fffu + ((u >> 16) & 1u)) >> 16);   // RNE
}

// --------------------------- weight transpose ------------------------------
__global__ __launch_bounds__(256) void transpose_bf16(
        const float* __restrict__ in, ushort* __restrict__ out, int R, int C) {
    int gid = blockIdx.x * 256 + threadIdx.x;
    if (gid >= R * C) return;
    int c = gid / R, r = gid - c * R;
    out[gid] = f2bf(in[(size_t)r * C + c]);
}

// ------------------------------ layernorm ----------------------------------
__global__ __launch_bounds__(256) void ln_kernel(
        const float* __restrict__ src, const float* __restrict__ ltn,
        const float* __restrict__ gs, const float* __restrict__ bs,
        const float* __restrict__ gl, const float* __restrict__ bl,
        ushort* __restrict__ ctx, ushort* __restrict__ qin) {
    int r = blockIdx.x * 4 + (threadIdx.x >> 6);
    int lane = threadIdx.x & 63;
    int bt = r / N_CTX;
    int i = r - bt * N_CTX;
    const float *x, *g, *b;
    int isl = (i >= N_SRC);
    if (!isl) { x = src + ((size_t)bt * N_SRC + i) * DIMK; g = gs; b = bs; }
    else      { x = ltn + ((size_t)bt * N_LTN + (i - N_SRC)) * DIMK; g = gl; b = bl; }
    float v[12]; float s = 0.f, s2 = 0.f;
#pragma unroll
    for (int t = 0; t < 12; t++) {
        float xv = x[lane + t * 64];
        v[t] = xv; s += xv; s2 += xv * xv;
    }
#pragma unroll
    for (int off = 32; off >= 1; off >>= 1) {
        s  += __shfl_xor(s,  off, 64);
        s2 += __shfl_xor(s2, off, 64);
    }
    float mu  = s * (1.0f / 768.0f);
    float var = s2 * (1.0f / 768.0f) - mu * mu;
    float rs  = rsqrtf(var + 1e-5f);
    ushort* crow = ctx + (size_t)r * DIMK;
    ushort* qrow = isl ? (qin + (size_t)(bt * N_LTN + (i - N_SRC)) * DIMK) : nullptr;
#pragma unroll
    for (int t = 0; t < 12; t++) {
        int idx = lane + t * 64;
        float y = (v[t] - mu) * rs * g[idx] + b[idx];
        ushort hb = f2bf(y);
        crow[idx] = hb;
        if (isl) qrow[idx] = hb;
    }
}

// ------------------------------- GEMM --------------------------------------
// C[M][N] = A[M][K] @ B[N][K]^T , A/B bf16, acc fp32. (verified R1)
template <typename CT>
__global__ __launch_bounds__(256) void gemm_bt(
        const ushort* __restrict__ A, const ushort* __restrict__ B,
        CT* __restrict__ C, int M, int N, int K) {
    __shared__ ushort lA[128 * 64];
    __shared__ ushort lB[128 * 64];
    int tid = threadIdx.x;
    int lane = tid & 63, wave = tid >> 6;
    int wm = wave >> 1, wn = wave & 1;
    int bm = blockIdx.x, bn = blockIdx.y;

    floatx4 acc[4][4];
#pragma unroll
    for (int mi = 0; mi < 4; mi++)
#pragma unroll
        for (int ni = 0; ni < 4; ni++) acc[mi][ni] = (floatx4){0.f, 0.f, 0.f, 0.f};

    int srow = lane >> 3;
    int schunk = (lane & 7) ^ srow;
    int quad = lane >> 4, lr = lane & 15;
    const int kiters = K >> 6;

    for (int kt = 0; kt < kiters; kt++) {
#pragma unroll
        for (int c2 = 0; c2 < 4; c2++) {
            int row = c2 * 32 + wave * 8 + srow;
            const ushort* gpA = A + ((size_t)(bm * 128 + row) * K + kt * 64 + schunk * 8);
            ushort* lpA = lA + (c2 * 32 + wave * 8) * 64 + lane * 8;
            __builtin_amdgcn_global_load_lds((gvoid*)gpA, (lvoid*)lpA, 16, 0, 0);
            const ushort* gpB = B + ((size_t)(bn * 128 + row) * K + kt * 64 + schunk * 8);
            ushort* lpB = lB + (c2 * 32 + wave * 8) * 64 + lane * 8;
            __builtin_amdgcn_global_load_lds((gvoid*)gpB, (lvoid*)lpB, 16, 0, 0);
        }
        __syncthreads();
#pragma unroll
        for (int ks = 0; ks < 2; ks++) {
            short8 av[4], bv[4];
            int slot = ((ks * 4 + quad) ^ (lane & 7)) * 8;
#pragma unroll
            for (int mi = 0; mi < 4; mi++)
                av[mi] = *(const short8*)(lA + (wm * 64 + mi * 16 + lr) * 64 + slot);
#pragma unroll
            for (int ni = 0; ni < 4; ni++)
                bv[ni] = *(const short8*)(lB + (wn * 64 + ni * 16 + lr) * 64 + slot);
#pragma unroll
            for (int mi = 0; mi < 4; mi++)
#pragma unroll
                for (int ni = 0; ni < 4; ni++)
                    acc[mi][ni] = __builtin_amdgcn_mfma_f32_16x16x32_bf16(
                        av[mi], bv[ni], acc[mi][ni], 0, 0, 0);
        }
        __syncthreads();
    }
#pragma unroll
    for (int mi = 0; mi < 4; mi++)
#pragma unroll
        for (int ni = 0; ni < 4; ni++)
#pragma unroll
            for (int r = 0; r < 4; r++) {
                int row = bm * 128 + wm * 64 + mi * 16 + quad * 4 + r;
                int col = bn * 128 + wn * 64 + ni * 16 + lr;
                float vv = acc[mi][ni][r];
                if constexpr (std::is_same<CT, ushort>::value)
                    C[(size_t)row * N + col] = f2bf(vv);
                else
                    C[(size_t)row * N + col] = vv;
            }
}

// ------------------------- flash attention (split-K) -----------------------
// grid (comb=bt*8+h, split). Per block: Q[64,64] frags in regs; loop over
// 128-key tiles: S=Q@K^T (MFMA), in-register online softmax, P->LDS (A-layout),
// O += P@V^T (MFMA, V^T staged in LDS). Emits unnormalized O~, m, l partials.
#define PR 136   // P/VT LDS row stride (ushorts); 272B: 16B-aligned, ~2-way banks

__global__ __launch_bounds__(256) void attn_flash(
        const float* __restrict__ qf, const ushort* __restrict__ kvb,
        float* __restrict__ Op, float* __restrict__ ml) {
    __shared__ ushort lK[128 * 64];
    __shared__ ushort lVT[64 * PR];
    __shared__ ushort lP[64 * PR];
    __shared__ float smax[64 * 4];
    __shared__ float psum[64 * 4];
    __shared__ float mnew[64];
    __shared__ float salpha[64];

    int comb = blockIdx.x, split = blockIdx.y;
    int bt = comb >> 3, h = comb & 7;
    int tid = threadIdx.x;
    int w = tid >> 6, lane = tid & 63, quad = lane >> 4, lr = lane & 15;

    const ushort* kptr = kvb + (size_t)bt * N_CTX * 1024 + h * 64;
    const ushort* vptr = kptr + 512;

    // Q A-frags: qa[mi][kc] ; m = mi*16+lr, k = kc*32+quad*8+j
    short8 qa[4][2];
    {
        const float* qbase = qf + (size_t)(bt * 64) * DEMB + h * 64;
#pragma unroll
        for (int mi = 0; mi < 4; mi++)
#pragma unroll
            for (int kc = 0; kc < 2; kc++) {
                const float* p = qbase + (size_t)(mi * 16 + lr) * DEMB + kc * 32 + quad * 8;
                float4 f0 = *(const float4*)p;
                float4 f1 = *(const float4*)(p + 4);
                short8 v;
                v[0] = f2bf(f0.x); v[1] = f2bf(f0.y); v[2] = f2bf(f0.z); v[3] = f2bf(f0.w);
                v[4] = f2bf(f1.x); v[5] = f2bf(f1.y); v[6] = f2bf(f1.z); v[7] = f2bf(f1.w);
                qa[mi][kc] = v;
            }
    }

    floatx4 accO[4];
#pragma unroll
    for (int nt = 0; nt < 4; nt++) accO[nt] = (floatx4){0.f, 0.f, 0.f, 0.f};
    float m_run = -1e30f, l_run = 0.f;   // meaningful in wave 0 (lane == q)

    int vp = tid & 63;    // key-pair index (keys 2vp, 2vp+1)
    int vdg = tid >> 6;   // d-group of 16

    for (int t = split; t < NTILES; t += NSPLIT) {
        int kbase = t * 128;
        __syncthreads();   // prev-iter LDS readers done before restaging

        // ---- stage K (swizzled, 8 lanes/key-row, global_load_lds 16B) ----
#pragma unroll
        for (int c2 = 0; c2 < 4; c2++) {
            int jloc = w * 32 + c2 * 8 + (lane >> 3);
            int chunk = (lane & 7) ^ ((lane >> 3) & 7);
            const ushort* gp = kptr + (size_t)(kbase + jloc) * 1024 + chunk * 8;
            ushort* lp = lK + (w * 32 + c2 * 8) * 64 + lane * 8;
            __builtin_amdgcn_global_load_lds((gvoid*)gp, (lvoid*)lp, 16, 0, 0);
        }

        // ---- stage V^T via pack-transpose (thread: key-pair x 16 dims) ----
        {
            int k0 = kbase + vp * 2;
            bool valid = (k0 + 1) < N_CTX;   // pairs never straddle (N_CTX even)
            const ushort* r0 = vptr + (size_t)k0 * 1024 + vdg * 16;
            const ushort* r1 = r0 + 1024;
            uint4 a0 = *(const uint4*)r0;
            uint4 a1 = *(const uint4*)(r0 + 8);
            uint4 b0 = *(const uint4*)r1;
            uint4 b1 = *(const uint4*)(r1 + 8);
            if (!valid) {
                a0 = make_uint4(0, 0, 0, 0); a1 = a0; b0 = a0; b1 = a0;
            }
            unsigned av8[8] = {a0.x, a0.y, a0.z, a0.w, a1.x, a1.y, a1.z, a1.w};
            unsigned bv8[8] = {b0.x, b0.y, b0.z, b0.w, b1.x, b1.y, b1.z, b1.w};
#pragma unroll
            for (int i = 0; i < 8; i++) {
                unsigned la = av8[i] & 0xffffu, ha = av8[i] >> 16;
                unsigned lb = bv8[i] & 0xffffu, hb = bv8[i] >> 16;
                *(unsigned*)(lVT + (vdg * 16 + 2 * i) * PR + vp * 2)     = la | (lb << 16);
                *(unsigned*)(lVT + (vdg * 16 + 2 * i + 1) * PR + vp * 2) = ha | (hb << 16);
            }
        }
        __syncthreads();   // staging complete

        // ---- S = Q @ K^T : wave w owns cols [w*32, w*32+32) of S[64][128] --
        floatx4 accS[4][2];
#pragma unroll
        for (int mi = 0; mi < 4; mi++)
#pragma unroll
            for (int nt = 0; nt < 2; nt++) accS[mi][nt] = (floatx4){0.f, 0.f, 0.f, 0.f};
#pragma unroll
        for (int kc = 0; kc < 2; kc++) {
            short8 bv[2];
#pragma unroll
            for (int nt = 0; nt < 2; nt++) {
                int kr = w * 32 + nt * 16 + lr;
                int slot = (kc * 4 + quad) ^ (kr & 7);
                bv[nt] = *(const short8*)(lK + kr * 64 + slot * 8);
            }
#pragma unroll
            for (int mi = 0; mi < 4; mi++)
#pragma unroll
                for (int nt = 0; nt < 2; nt++)
                    accS[mi][nt] = __builtin_amdgcn_mfma_f32_16x16x32_bf16(
                        qa[mi][kc], bv[nt], accS[mi][nt], 0, 0, 0);
        }

        // ---- mask + scale; wave-local row max over 32 cols ----
        bool v0 = (kbase + w * 32 + lr) < N_CTX;
        bool v1 = (kbase + w * 32 + 16 + lr) < N_CTX;
        float sc[4][2][4];
#pragma unroll
        for (int mi = 0; mi < 4; mi++)
#pragma unroll
            for (int r = 0; r < 4; r++) {
                sc[mi][0][r] = v0 ? accS[mi][0][r] * 0.125f : -1e30f;
                sc[mi][1][r] = v1 ? accS[mi][1][r] * 0.125f : -1e30f;
            }
#pragma unroll
        for (int mi = 0; mi < 4; mi++)
#pragma unroll
            for (int r = 0; r < 4; r++) {
                float m = fmaxf(sc[mi][0][r], sc[mi][1][r]);
#pragma unroll
                for (int d = 1; d < 16; d <<= 1) m = fmaxf(m, __shfl_xor(m, d, 64));
                if (lr == 0) smax[(mi * 16 + quad * 4 + r) * 4 + w] = m;
            }
        __syncthreads();

        // ---- wave 0: combine maxes, update running m, compute alpha ----
        if (w == 0) {
            float4 s4 = *(const float4*)(smax + lane * 4);
            float mt = fmaxf(fmaxf(s4.x, s4.y), fmaxf(s4.z, s4.w));
            float mn = fmaxf(m_run, mt);
            salpha[lane] = __expf(m_run - mn);
            m_run = mn;
            mnew[lane] = mn;
        }
        __syncthreads();

        // ---- P = exp(sc - m); partial row sums; P -> LDS; rescale O ----
#pragma unroll
        for (int mi = 0; mi < 4; mi++)
#pragma unroll
            for (int r = 0; r < 4; r++) {
                int row = mi * 16 + quad * 4 + r;
                float mrow = mnew[row];
                float p0 = __expf(sc[mi][0][r] - mrow);
                float p1 = __expf(sc[mi][1][r] - mrow);
                lP[row * PR + w * 32 + lr]      = f2bf(p0);
                lP[row * PR + w * 32 + 16 + lr] = f2bf(p1);
                float s = p0 + p1;
#pragma unroll
                for (int d = 1; d < 16; d <<= 1) s += __shfl_xor(s, d, 64);
                if (lr == 0) psum[row * 4 + w] = s;
            }
        {
            float a0 = salpha[w * 16 + quad * 4 + 0];
            float a1 = salpha[w * 16 + quad * 4 + 1];
            float a2 = salpha[w * 16 + quad * 4 + 2];
            float a3 = salpha[w * 16 + quad * 4 + 3];
#pragma unroll
            for (int nt = 0; nt < 4; nt++) {
                accO[nt][0] *= a0; accO[nt][1] *= a1;
                accO[nt][2] *= a2; accO[nt][3] *= a3;
            }
        }
        __syncthreads();

        // ---- wave 0: l update ----
        if (w == 0) {
            float4 p4 = *(const float4*)(psum + lane * 4);
            l_run = l_run * salpha[lane] + (p4.x + p4.y + p4.z + p4.w);
        }

        // ---- O += P @ V^T : wave w owns O rows [w*16, w*16+16) ----
        short8 av[4];
#pragma unroll
        for (int kc = 0; kc < 4; kc++)
            av[kc] = *(const short8*)(lP + (w * 16 + lr) * PR + kc * 32 + quad * 8);
#pragma unroll
        for (int nt = 0; nt < 4; nt++)
#pragma unroll
            for (int kc = 0; kc < 4; kc++) {
                short8 bv = *(const short8*)(lVT + (nt * 16 + lr) * PR + kc * 32 + quad * 8);
                accO[nt] = __builtin_amdgcn_mfma_f32_16x16x32_bf16(av[kc], bv, accO[nt], 0, 0, 0);
            }
    }

    // ---- store partials ----
    float* opb = Op + (size_t)(comb * NSPLIT + split) * 64 * 64;
#pragma unroll
    for (int nt = 0; nt < 4; nt++)
#pragma unroll
        for (int r = 0; r < 4; r++)
            opb[(w * 16 + quad * 4 + r) * 64 + nt * 16 + lr] = accO[nt][r];
    if (w == 0) {
        float* mlp = ml + ((size_t)(comb * NSPLIT + split) * 64 + lane) * 2;
        mlp[0] = m_run; mlp[1] = l_run;
    }
}

// merge NSPLIT partials per (comb, q): out = sum_s w_s O_s / sum_s w_s l_s
__global__ __launch_bounds__(64) void attn_combine(
        const float* __restrict__ Op, const float* __restrict__ ml,
        ushort* __restrict__ outp) {
    int bx = blockIdx.x;
    int comb = bx >> 6, q = bx & 63;
    int bt = comb >> 3, h = comb & 7;
    int d = threadIdx.x;
    float mv[NSPLIT], lv[NSPLIT];
    float M = -1e30f;
#pragma unroll
    for (int s = 0; s < NSPLIT; s++) {
        const float* p = ml + ((size_t)(comb * NSPLIT + s) * 64 + q) * 2;
        mv[s] = p[0]; lv[s] = p[1];
        M = fmaxf(M, mv[s]);
    }
    float L = 0.f, O = 0.f;
#pragma unroll
    for (int s = 0; s < NSPLIT; s++) {
        float wgt = __expf(mv[s] - M);
        L += wgt * lv[s];
        O += wgt * Op[((size_t)(comb * NSPLIT + s) * 64 + q) * 64 + d];
    }
    outp[(size_t)(bt * 64 + q) * DEMB + h * 64 + d] = f2bf(O / L);
}

// ------------------------------ launcher -----------------------------------
extern "C" void kernel_launch(void* const* d_in, const int* in_sizes, int n_in,
                              void* d_out, int out_size, void* d_ws, size_t ws_size,
                              hipStream_t stream) {
    const float* src   = (const float*)d_in[0];
    const float* ltn   = (const float*)d_in[1];
    const float* g_src = (const float*)d_in[2];
    const float* b_src = (const float*)d_in[3];
    const float* g_ltn = (const float*)d_in[4];
    const float* b_ltn = (const float*)d_in[5];
    const float* Wq    = (const float*)d_in[6];
    const float* Wkv   = (const float*)d_in[7];
    const float* Wo    = (const float*)d_in[8];
    float* out = (float*)d_out;

    char* ws = (char*)d_ws;
    size_t off = 0;
    auto alloc = [&](size_t bytes) -> void* {
        void* p = ws + off;
        off += (bytes + 255) & ~(size_t)255;
        return p;
    };
    ushort* ctx  = (ushort*)alloc((size_t)MROWS * DIMK * 2);   // 101.4 MB
    ushort* qin  = (ushort*)alloc((size_t)512 * DIMK * 2);
    ushort* WkvT = (ushort*)alloc((size_t)1024 * DIMK * 2);
    ushort* WqT  = (ushort*)alloc((size_t)512 * DIMK * 2);
    ushort* WoT  = (ushort*)alloc((size_t)768 * DEMB * 2);
    ushort* kvb  = (ushort*)alloc((size_t)MROWS * 1024 * 2);   // 135.3 MB
    float*  qf   = (float*) alloc((size_t)512 * DEMB * 4);
    ushort* outp = (ushort*)alloc((size_t)512 * DEMB * 2);

    // attention partials alias the ctx buffer (dead after the two GEMMs below)
    float* Op  = (float*)(void*)ctx;                       // 64*16*64*64 f32 = 16.8 MB
    float* mlb = Op + (size_t)64 * NSPLIT * 64 * 64;       // 64*16*64*2 f32

    transpose_bf16<<<(768 * 1024 + 255) / 256, 256, 0, stream>>>(Wkv, WkvT, 768, 1024);
    transpose_bf16<<<(768 * 512 + 255) / 256, 256, 0, stream>>>(Wq, WqT, 768, 512);
    transpose_bf16<<<(512 * 768 + 255) / 256, 256, 0, stream>>>(Wo, WoT, 512, 768);

    ln_kernel<<<MROWS / 4, 256, 0, stream>>>(src, ltn, g_src, b_src, g_ltn, b_ltn, ctx, qin);

    gemm_bt<ushort><<<dim3(MROWS / 128, 1024 / 128), 256, 0, stream>>>(
        ctx, WkvT, kvb, MROWS, 1024, DIMK);
    gemm_bt<float><<<dim3(512 / 128, 512 / 128), 256, 0, stream>>>(
        qin, WqT, qf, 512, 512, DIMK);

    attn_flash<<<dim3(64, NSPLIT), 256, 0, stream>>>(qf, kvb, Op, mlb);
    attn_combine<<<4096, 64, 0, stream>>>(Op, mlb, outp);

    gemm_bt<float><<<dim3(512 / 128, 768 / 128), 256, 0, stream>>>(
        outp, WoT, out, 512, 768, DEMB);
}

// Round 4
// 568.518 us; speedup vs baseline: 2.7337x; 1.0262x over previous
//
#include <hip/hip_runtime.h>
#include <hip/hip_bf16.h>
#include <type_traits>

// ---------------------------------------------------------------------------
// PerceiverAttention on MI355X.
// Pipeline:
//   1) transpose_all     : Wkv/Wq/Wo -> bf16 [N][K] layouts (one LDS-tiled kernel)
//   2) ln_kernel         : LayerNorm src+ltn -> ctx bf16 [66048][768]; ltn rows
//                          also compacted into qin bf16 [512][768]
//   3) gemm_bt<ushort>   : kv  = ctx @ WkvT^T   -> bf16 [66048][1024]
//   4) gemm_bt<float>    : q   = qin @ WqT^T    -> f32  [512][512]
//   5) attn_flash        : split-K MFMA flash attention -> partials (O~,m,l)
//      attn_combine      : merge 32 splits -> out_pre bf16 [512][512]
//   6) gemm_bt<float>    : out = out_pre @ WoT^T -> f32 d_out [512][768]
// ---------------------------------------------------------------------------

#define N_SRC 8192
#define N_LTN 64
#define N_CTX 8256            // per (b,t)
#define NBT 8                 // b*t
#define MROWS 66048           // NBT * N_CTX
#define DIMK 768
#define DEMB 512
#define NSPLIT 32
#define NTILES 65             // ceil(N_CTX / 128)

typedef short short8 __attribute__((ext_vector_type(8)));
typedef float floatx4 __attribute__((ext_vector_type(4)));
typedef __attribute__((address_space(1))) void gvoid;
typedef __attribute__((address_space(3))) void lvoid;

__device__ inline ushort f2bf(float f) {
    union { float f; unsigned u; } v; v.f = f;
    unsigned u = v.u;
    return (ushort)((u + 0x7fffu + ((u >> 16) & 1u)) >> 16);   // RNE
}

// --------------------------- weight transposes -----------------------------
// One kernel, 64x64 LDS tiles, coalesced read AND write.
// z=0: Wkv fp32[768][1024] -> bf16[1024][768]
// z=1: Wq  fp32[768][512]  -> bf16[512][768]
// z=2: Wo  fp32[512][768]  -> bf16[768][512]
__global__ __launch_bounds__(256) void transpose_all(
        const float* __restrict__ Wkv, const float* __restrict__ Wq,
        const float* __restrict__ Wo, ushort* __restrict__ WkvT,
        ushort* __restrict__ WqT, ushort* __restrict__ WoT) {
    __shared__ ushort tile[64][65];
    int z = blockIdx.z;
    const float* in; ushort* out; int R, C;
    if (z == 0)      { in = Wkv; out = WkvT; R = 768; C = 1024; }
    else if (z == 1) { in = Wq;  out = WqT;  R = 768; C = 512;  }
    else             { in = Wo;  out = WoT;  R = 512; C = 768;  }
    int C0 = blockIdx.x * 64, R0 = blockIdx.y * 64;
    if (C0 >= C || R0 >= R) return;
    int tc = threadIdx.x & 63, tr4 = threadIdx.x >> 6;
#pragma unroll
    for (int j = 0; j < 16; j++) {
        int r = tr4 + j * 4;
        tile[r][tc] = f2bf(in[(size_t)(R0 + r) * C + C0 + tc]);
    }
    __syncthreads();
#pragma unroll
    for (int j = 0; j < 16; j++) {
        int c = tr4 + j * 4;
        out[(size_t)(C0 + c) * R + R0 + tc] = tile[tc][c];
    }
}

// ------------------------------ layernorm ----------------------------------
// one wave per row; 4 rows per 256-thread block; float4 / ushort4 vectorized
__global__ __launch_bounds__(256) void ln_kernel(
        const float* __restrict__ src, const float* __restrict__ ltn,
        const float* __restrict__ gs, const float* __restrict__ bs,
        const float* __restrict__ gl, const float* __restrict__ bl,
        ushort* __restrict__ ctx, ushort* __restrict__ qin) {
    int r = blockIdx.x * 4 + (threadIdx.x >> 6);
    int lane = threadIdx.x & 63;
    int bt = r / N_CTX;
    int i = r - bt * N_CTX;
    const float *x, *g, *b;
    int isl = (i >= N_SRC);
    if (!isl) { x = src + ((size_t)bt * N_SRC + i) * DIMK; g = gs; b = bs; }
    else      { x = ltn + ((size_t)bt * N_LTN + (i - N_SRC)) * DIMK; g = gl; b = bl; }
    float4 v[3]; float s = 0.f, s2 = 0.f;
#pragma unroll
    for (int t = 0; t < 3; t++) {
        float4 xv = *(const float4*)(x + t * 256 + lane * 4);
        v[t] = xv;
        s  += xv.x + xv.y + xv.z + xv.w;
        s2 += xv.x * xv.x + xv.y * xv.y + xv.z * xv.z + xv.w * xv.w;
    }
#pragma unroll
    for (int off = 32; off >= 1; off >>= 1) {
        s  += __shfl_xor(s,  off, 64);
        s2 += __shfl_xor(s2, off, 64);
    }
    float mu  = s * (1.0f / 768.0f);
    float var = s2 * (1.0f / 768.0f) - mu * mu;
    float rs  = rsqrtf(var + 1e-5f);
    ushort* crow = ctx + (size_t)r * DIMK;
    ushort* qrow = isl ? (qin + (size_t)(bt * N_LTN + (i - N_SRC)) * DIMK) : nullptr;
#pragma unroll
    for (int t = 0; t < 3; t++) {
        int idx = t * 256 + lane * 4;
        float4 gv = *(const float4*)(g + idx);
        float4 bv = *(const float4*)(b + idx);
        ushort4 u;
        u.x = f2bf((v[t].x - mu) * rs * gv.x + bv.x);
        u.y = f2bf((v[t].y - mu) * rs * gv.y + bv.y);
        u.z = f2bf((v[t].z - mu) * rs * gv.z + bv.z);
        u.w = f2bf((v[t].w - mu) * rs * gv.w + bv.w);
        *(ushort4*)(crow + idx) = u;
        if (isl) *(ushort4*)(qrow + idx) = u;
    }
}

// ------------------------------- GEMM --------------------------------------
// C[M][N] = A[M][K] @ B[N][K]^T , A/B bf16, acc fp32.
// NOTE: grid is (N/128, M/128) — N-tile on blockIdx.x (fastest) so consecutive
// blocks (≈ one per XCD) share the same A slab; B column stays L2-resident.
template <typename CT>
__global__ __launch_bounds__(256) void gemm_bt(
        const ushort* __restrict__ A, const ushort* __restrict__ B,
        CT* __restrict__ C, int M, int N, int K) {
    __shared__ ushort lA[128 * 64];
    __shared__ ushort lB[128 * 64];
    int tid = threadIdx.x;
    int lane = tid & 63, wave = tid >> 6;
    int wm = wave >> 1, wn = wave & 1;
    int bn = blockIdx.x, bm = blockIdx.y;

    floatx4 acc[4][4];
#pragma unroll
    for (int mi = 0; mi < 4; mi++)
#pragma unroll
        for (int ni = 0; ni < 4; ni++) acc[mi][ni] = (floatx4){0.f, 0.f, 0.f, 0.f};

    int srow = lane >> 3;
    int schunk = (lane & 7) ^ srow;
    int quad = lane >> 4, lr = lane & 15;
    const int kiters = K >> 6;

    for (int kt = 0; kt < kiters; kt++) {
#pragma unroll
        for (int c2 = 0; c2 < 4; c2++) {
            int row = c2 * 32 + wave * 8 + srow;
            const ushort* gpA = A + ((size_t)(bm * 128 + row) * K + kt * 64 + schunk * 8);
            ushort* lpA = lA + (c2 * 32 + wave * 8) * 64 + lane * 8;
            __builtin_amdgcn_global_load_lds((gvoid*)gpA, (lvoid*)lpA, 16, 0, 0);
            const ushort* gpB = B + ((size_t)(bn * 128 + row) * K + kt * 64 + schunk * 8);
            ushort* lpB = lB + (c2 * 32 + wave * 8) * 64 + lane * 8;
            __builtin_amdgcn_global_load_lds((gvoid*)gpB, (lvoid*)lpB, 16, 0, 0);
        }
        __syncthreads();
#pragma unroll
        for (int ks = 0; ks < 2; ks++) {
            short8 av[4], bv[4];
            int slot = ((ks * 4 + quad) ^ (lane & 7)) * 8;
#pragma unroll
            for (int mi = 0; mi < 4; mi++)
                av[mi] = *(const short8*)(lA + (wm * 64 + mi * 16 + lr) * 64 + slot);
#pragma unroll
            for (int ni = 0; ni < 4; ni++)
                bv[ni] = *(const short8*)(lB + (wn * 64 + ni * 16 + lr) * 64 + slot);
#pragma unroll
            for (int mi = 0; mi < 4; mi++)
#pragma unroll
                for (int ni = 0; ni < 4; ni++)
                    acc[mi][ni] = __builtin_amdgcn_mfma_f32_16x16x32_bf16(
                        av[mi], bv[ni], acc[mi][ni], 0, 0, 0);
        }
        __syncthreads();
    }
#pragma unroll
    for (int mi = 0; mi < 4; mi++)
#pragma unroll
        for (int ni = 0; ni < 4; ni++)
#pragma unroll
            for (int r = 0; r < 4; r++) {
                int row = bm * 128 + wm * 64 + mi * 16 + quad * 4 + r;
                int col = bn * 128 + wn * 64 + ni * 16 + lr;
                float vv = acc[mi][ni][r];
                if constexpr (std::is_same<CT, ushort>::value)
                    C[(size_t)row * N + col] = f2bf(vv);
                else
                    C[(size_t)row * N + col] = vv;
            }
}

// ------------------------- flash attention (split-K) -----------------------
// grid (comb=bt*8+h, split). Per block: Q[64,64] frags in regs; loop over
// 128-key tiles: S=Q@K^T (MFMA), in-register online softmax, P->LDS (A-layout),
// O += P@V^T (MFMA, V^T staged in LDS). Emits unnormalized O~, m, l partials.
// PR = row stride for lP/lVT tiles, which are [64][128]: must be >= 128!
// 136 = 128 + 8: 272B rows stay 16B-aligned for ds_read_b128, ~2-way banks (free).
#define PR 136

__global__ __launch_bounds__(256) void attn_flash(
        const float* __restrict__ qf, const ushort* __restrict__ kvb,
        float* __restrict__ Op, float* __restrict__ ml) {
    __shared__ ushort lK[128 * 64];
    __shared__ ushort lVT[64 * PR];
    __shared__ ushort lP[64 * PR];
    __shared__ float smax[64 * 4];
    __shared__ float psum[64 * 4];
    __shared__ float mnew[64];
    __shared__ float salpha[64];

    int comb = blockIdx.x, split = blockIdx.y;
    int bt = comb >> 3, h = comb & 7;
    int tid = threadIdx.x;
    int w = tid >> 6, lane = tid & 63, quad = lane >> 4, lr = lane & 15;

    const ushort* kptr = kvb + (size_t)bt * N_CTX * 1024 + h * 64;
    const ushort* vptr = kptr + 512;

    // Q A-frags: qa[mi][kc] ; m = mi*16+lr, k = kc*32+quad*8+j
    short8 qa[4][2];
    {
        const float* qbase = qf + (size_t)(bt * 64) * DEMB + h * 64;
#pragma unroll
        for (int mi = 0; mi < 4; mi++)
#pragma unroll
            for (int kc = 0; kc < 2; kc++) {
                const float* p = qbase + (size_t)(mi * 16 + lr) * DEMB + kc * 32 + quad * 8;
                float4 f0 = *(const float4*)p;
                float4 f1 = *(const float4*)(p + 4);
                short8 v;
                v[0] = f2bf(f0.x); v[1] = f2bf(f0.y); v[2] = f2bf(f0.z); v[3] = f2bf(f0.w);
                v[4] = f2bf(f1.x); v[5] = f2bf(f1.y); v[6] = f2bf(f1.z); v[7] = f2bf(f1.w);
                qa[mi][kc] = v;
            }
    }

    floatx4 accO[4];
#pragma unroll
    for (int nt = 0; nt < 4; nt++) accO[nt] = (floatx4){0.f, 0.f, 0.f, 0.f};
    float m_run = -1e30f, l_run = 0.f;   // meaningful in wave 0 (lane == q)

    int vp = tid & 63;    // key-pair index (keys 2vp, 2vp+1)
    int vdg = tid >> 6;   // d-group of 16

    for (int t = split; t < NTILES; t += NSPLIT) {
        int kbase = t * 128;
        __syncthreads();   // prev-iter LDS readers done before restaging

        // ---- stage K (swizzled, 8 lanes/key-row, global_load_lds 16B) ----
#pragma unroll
        for (int c2 = 0; c2 < 4; c2++) {
            int jloc = w * 32 + c2 * 8 + (lane >> 3);
            int chunk = (lane & 7) ^ ((lane >> 3) & 7);
            int jg = kbase + jloc; if (jg > N_CTX - 1) jg = N_CTX - 1;  // clamp tail
            const ushort* gp = kptr + (size_t)jg * 1024 + chunk * 8;
            ushort* lp = lK + (w * 32 + c2 * 8) * 64 + lane * 8;
            __builtin_amdgcn_global_load_lds((gvoid*)gp, (lvoid*)lp, 16, 0, 0);
        }

        // ---- stage V^T via pack-transpose (thread: key-pair x 16 dims) ----
        {
            int k0 = kbase + vp * 2;
            bool valid = (k0 + 1) < N_CTX;   // pairs never straddle (N_CTX even)
            int k0c = valid ? k0 : (N_CTX - 2);
            const ushort* r0 = vptr + (size_t)k0c * 1024 + vdg * 16;
            const ushort* r1 = r0 + 1024;
            uint4 a0 = *(const uint4*)r0;
            uint4 a1 = *(const uint4*)(r0 + 8);
            uint4 b0 = *(const uint4*)r1;
            uint4 b1 = *(const uint4*)(r1 + 8);
            if (!valid) {
                a0 = make_uint4(0, 0, 0, 0); a1 = a0; b0 = a0; b1 = a0;
            }
            unsigned av8[8] = {a0.x, a0.y, a0.z, a0.w, a1.x, a1.y, a1.z, a1.w};
            unsigned bv8[8] = {b0.x, b0.y, b0.z, b0.w, b1.x, b1.y, b1.z, b1.w};
#pragma unroll
            for (int i = 0; i < 8; i++) {
                unsigned la = av8[i] & 0xffffu, ha = av8[i] >> 16;
                unsigned lb = bv8[i] & 0xffffu, hb = bv8[i] >> 16;
                *(unsigned*)(lVT + (vdg * 16 + 2 * i) * PR + vp * 2)     = la | (lb << 16);
                *(unsigned*)(lVT + (vdg * 16 + 2 * i + 1) * PR + vp * 2) = ha | (hb << 16);
            }
        }
        __syncthreads();   // staging complete

        // ---- S = Q @ K^T : wave w owns cols [w*32, w*32+32) of S[64][128] --
        floatx4 accS[4][2];
#pragma unroll
        for (int mi = 0; mi < 4; mi++)
#pragma unroll
            for (int nt = 0; nt < 2; nt++) accS[mi][nt] = (floatx4){0.f, 0.f, 0.f, 0.f};
#pragma unroll
        for (int kc = 0; kc < 2; kc++) {
            short8 bv[2];
#pragma unroll
            for (int nt = 0; nt < 2; nt++) {
                int kr = w * 32 + nt * 16 + lr;
                int slot = (kc * 4 + quad) ^ (kr & 7);
                bv[nt] = *(const short8*)(lK + kr * 64 + slot * 8);
            }
#pragma unroll
            for (int mi = 0; mi < 4; mi++)
#pragma unroll
                for (int nt = 0; nt < 2; nt++)
                    accS[mi][nt] = __builtin_amdgcn_mfma_f32_16x16x32_bf16(
                        qa[mi][kc], bv[nt], accS[mi][nt], 0, 0, 0);
        }

        // ---- mask + scale; wave-local row max over 32 cols ----
        bool v0 = (kbase + w * 32 + lr) < N_CTX;
        bool v1 = (kbase + w * 32 + 16 + lr) < N_CTX;
        float sc[4][2][4];
#pragma unroll
        for (int mi = 0; mi < 4; mi++)
#pragma unroll
            for (int r = 0; r < 4; r++) {
                sc[mi][0][r] = v0 ? accS[mi][0][r] * 0.125f : -1e30f;
                sc[mi][1][r] = v1 ? accS[mi][1][r] * 0.125f : -1e30f;
            }
#pragma unroll
        for (int mi = 0; mi < 4; mi++)
#pragma unroll
            for (int r = 0; r < 4; r++) {
                float m = fmaxf(sc[mi][0][r], sc[mi][1][r]);
#pragma unroll
                for (int d = 1; d < 16; d <<= 1) m = fmaxf(m, __shfl_xor(m, d, 64));
                if (lr == 0) smax[(mi * 16 + quad * 4 + r) * 4 + w] = m;
            }
        __syncthreads();

        // ---- wave 0: combine maxes, update running m, compute alpha ----
        if (w == 0) {
            float4 s4 = *(const float4*)(smax + lane * 4);
            float mt = fmaxf(fmaxf(s4.x, s4.y), fmaxf(s4.z, s4.w));
            float mn = fmaxf(m_run, mt);
            salpha[lane] = __expf(m_run - mn);
            m_run = mn;
            mnew[lane] = mn;
        }
        __syncthreads();

        // ---- P = exp(sc - m); partial row sums; P -> LDS; rescale O ----
#pragma unroll
        for (int mi = 0; mi < 4; mi++)
#pragma unroll
            for (int r = 0; r < 4; r++) {
                int row = mi * 16 + quad * 4 + r;
                float mrow = mnew[row];
                float p0 = __expf(sc[mi][0][r] - mrow);
                float p1 = __expf(sc[mi][1][r] - mrow);
                lP[row * PR + w * 32 + lr]      = f2bf(p0);
                lP[row * PR + w * 32 + 16 + lr] = f2bf(p1);
                float s = p0 + p1;
#pragma unroll
                for (int d = 1; d < 16; d <<= 1) s += __shfl_xor(s, d, 64);
                if (lr == 0) psum[row * 4 + w] = s;
            }
        {
            float a0 = salpha[w * 16 + quad * 4 + 0];
            float a1 = salpha[w * 16 + quad * 4 + 1];
            float a2 = salpha[w * 16 + quad * 4 + 2];
            float a3 = salpha[w * 16 + quad * 4 + 3];
#pragma unroll
            for (int nt = 0; nt < 4; nt++) {
                accO[nt][0] *= a0; accO[nt][1] *= a1;
                accO[nt][2] *= a2; accO[nt][3] *= a3;
            }
        }
        __syncthreads();

        // ---- wave 0: l update ----
        if (w == 0) {
            float4 p4 = *(const float4*)(psum + lane * 4);
            l_run = l_run * salpha[lane] + (p4.x + p4.y + p4.z + p4.w);
        }

        // ---- O += P @ V^T : wave w owns O rows [w*16, w*16+16) ----
        short8 av[4];
#pragma unroll
        for (int kc = 0; kc < 4; kc++)
            av[kc] = *(const short8*)(lP + (w * 16 + lr) * PR + kc * 32 + quad * 8);
#pragma unroll
        for (int nt = 0; nt < 4; nt++)
#pragma unroll
            for (int kc = 0; kc < 4; kc++) {
                short8 bv = *(const short8*)(lVT + (nt * 16 + lr) * PR + kc * 32 + quad * 8);
                accO[nt] = __builtin_amdgcn_mfma_f32_16x16x32_bf16(av[kc], bv, accO[nt], 0, 0, 0);
            }
    }

    // ---- store partials ----
    float* opb = Op + (size_t)(comb * NSPLIT + split) * 64 * 64;
#pragma unroll
    for (int nt = 0; nt < 4; nt++)
#pragma unroll
        for (int r = 0; r < 4; r++)
            opb[(w * 16 + quad * 4 + r) * 64 + nt * 16 + lr] = accO[nt][r];
    if (w == 0) {
        float* mlp = ml + ((size_t)(comb * NSPLIT + split) * 64 + lane) * 2;
        mlp[0] = m_run; mlp[1] = l_run;
    }
}

// merge NSPLIT partials per (comb, q): out = sum_s w_s O_s / sum_s w_s l_s
__global__ __launch_bounds__(64) void attn_combine(
        const float* __restrict__ Op, const float* __restrict__ ml,
        ushort* __restrict__ outp) {
    int bx = blockIdx.x;
    int comb = bx >> 6, q = bx & 63;
    int bt = comb >> 3, h = comb & 7;
    int d = threadIdx.x;
    float M = -1e30f;
    for (int s = 0; s < NSPLIT; s++)
        M = fmaxf(M, ml[((size_t)(comb * NSPLIT + s) * 64 + q) * 2]);
    float L = 0.f, O = 0.f;
    for (int s = 0; s < NSPLIT; s++) {
        const float* p = ml + ((size_t)(comb * NSPLIT + s) * 64 + q) * 2;
        float wgt = __expf(p[0] - M);
        L = fmaf(wgt, p[1], L);
        O = fmaf(wgt, Op[((size_t)(comb * NSPLIT + s) * 64 + q) * 64 + d], O);
    }
    outp[(size_t)(bt * 64 + q) * DEMB + h * 64 + d] = f2bf(O / L);
}

// ------------------------------ launcher -----------------------------------
extern "C" void kernel_launch(void* const* d_in, const int* in_sizes, int n_in,
                              void* d_out, int out_size, void* d_ws, size_t ws_size,
                              hipStream_t stream) {
    const float* src   = (const float*)d_in[0];
    const float* ltn   = (const float*)d_in[1];
    const float* g_src = (const float*)d_in[2];
    const float* b_src = (const float*)d_in[3];
    const float* g_ltn = (const float*)d_in[4];
    const float* b_ltn = (const float*)d_in[5];
    const float* Wq    = (const float*)d_in[6];
    const float* Wkv   = (const float*)d_in[7];
    const float* Wo    = (const float*)d_in[8];
    float* out = (float*)d_out;

    char* ws = (char*)d_ws;
    size_t off = 0;
    auto alloc = [&](size_t bytes) -> void* {
        void* p = ws + off;
        off += (bytes + 255) & ~(size_t)255;
        return p;
    };
    ushort* ctx  = (ushort*)alloc((size_t)MROWS * DIMK * 2);   // 101.4 MB
    ushort* qin  = (ushort*)alloc((size_t)512 * DIMK * 2);
    ushort* WkvT = (ushort*)alloc((size_t)1024 * DIMK * 2);
    ushort* WqT  = (ushort*)alloc((size_t)512 * DIMK * 2);
    ushort* WoT  = (ushort*)alloc((size_t)768 * DEMB * 2);
    ushort* kvb  = (ushort*)alloc((size_t)MROWS * 1024 * 2);   // 135.3 MB
    float*  qf   = (float*) alloc((size_t)512 * DEMB * 4);
    ushort* outp = (ushort*)alloc((size_t)512 * DEMB * 2);

    // attention partials alias the ctx buffer (dead after the two GEMMs below)
    float* Op  = (float*)(void*)ctx;                       // 64*32*64*64 f32 = 33.6 MB
    float* mlb = Op + (size_t)64 * NSPLIT * 64 * 64;       // 64*32*64*2 f32 = 1 MB

    transpose_all<<<dim3(16, 12, 3), 256, 0, stream>>>(Wkv, Wq, Wo, WkvT, WqT, WoT);

    ln_kernel<<<MROWS / 4, 256, 0, stream>>>(src, ltn, g_src, b_src, g_ltn, b_ltn, ctx, qin);

    gemm_bt<ushort><<<dim3(1024 / 128, MROWS / 128), 256, 0, stream>>>(
        ctx, WkvT, kvb, MROWS, 1024, DIMK);
    gemm_bt<float><<<dim3(512 / 128, 512 / 128), 256, 0, stream>>>(
        qin, WqT, qf, 512, 512, DIMK);

    attn_flash<<<dim3(64, NSPLIT), 256, 0, stream>>>(qf, kvb, Op, mlb);
    attn_combine<<<4096, 64, 0, stream>>>(Op, mlb, outp);

    gemm_bt<float><<<dim3(768 / 128, 512 / 128), 256, 0, stream>>>(
        outp, WoT, out, 512, 768, DEMB);
}

// Round 5
// 531.161 us; speedup vs baseline: 2.9260x; 1.0703x over previous
//
#include <hip/hip_runtime.h>
#include <hip/hip_bf16.h>
#include <type_traits>

// ---------------------------------------------------------------------------
// PerceiverAttention on MI355X.
// Pipeline:
//   1) transpose_all     : Wkv/Wq/Wo -> bf16 [N][K] layouts (one LDS-tiled kernel)
//   2) ln_kernel         : LayerNorm src+ltn -> ctx bf16 [66048][768]; ltn rows
//                          also compacted into qin bf16 [512][768]
//   3) gemm_bt<ushort>   : kv  = ctx @ WkvT^T   -> bf16 [66048][1024]
//   4) gemm_bt<float>    : q   = qin @ WqT^T    -> f32  [512][512]
//   5) attn_flash        : split-K MFMA flash attention, WAVE-LOCAL softmax
//                          (2 barriers/tile) -> partials (O~,m,l)
//      attn_combine      : merge 16 splits -> out_pre bf16 [512][512]
//   6) gemm_bt<float>    : out = out_pre @ WoT^T -> f32 d_out [512][768]
// ---------------------------------------------------------------------------

#define N_SRC 8192
#define N_LTN 64
#define N_CTX 8256            // per (b,t)
#define NBT 8                 // b*t
#define MROWS 66048           // NBT * N_CTX
#define DIMK 768
#define DEMB 512
#define NSPLIT 16
#define NTILES 65             // ceil(N_CTX / 128)

typedef short short8 __attribute__((ext_vector_type(8)));
typedef float floatx4 __attribute__((ext_vector_type(4)));
typedef __attribute__((address_space(1))) void gvoid;
typedef __attribute__((address_space(3))) void lvoid;

__device__ inline ushort f2bf(float f) {
    union { float f; unsigned u; } v; v.f = f;
    unsigned u = v.u;
    return (ushort)((u + 0x7fffu + ((u >> 16) & 1u)) >> 16);   // RNE
}

// --------------------------- weight transposes -----------------------------
// One kernel, 64x64 LDS tiles, coalesced read AND write.
__global__ __launch_bounds__(256) void transpose_all(
        const float* __restrict__ Wkv, const float* __restrict__ Wq,
        const float* __restrict__ Wo, ushort* __restrict__ WkvT,
        ushort* __restrict__ WqT, ushort* __restrict__ WoT) {
    __shared__ ushort tile[64][65];
    int z = blockIdx.z;
    const float* in; ushort* out; int R, C;
    if (z == 0)      { in = Wkv; out = WkvT; R = 768; C = 1024; }
    else if (z == 1) { in = Wq;  out = WqT;  R = 768; C = 512;  }
    else             { in = Wo;  out = WoT;  R = 512; C = 768;  }
    int C0 = blockIdx.x * 64, R0 = blockIdx.y * 64;
    if (C0 >= C || R0 >= R) return;
    int tc = threadIdx.x & 63, tr4 = threadIdx.x >> 6;
#pragma unroll
    for (int j = 0; j < 16; j++) {
        int r = tr4 + j * 4;
        tile[r][tc] = f2bf(in[(size_t)(R0 + r) * C + C0 + tc]);
    }
    __syncthreads();
#pragma unroll
    for (int j = 0; j < 16; j++) {
        int c = tr4 + j * 4;
        out[(size_t)(C0 + c) * R + R0 + tc] = tile[tc][c];
    }
}

// ------------------------------ layernorm ----------------------------------
// one wave per row; 4 rows per 256-thread block; float4 / ushort4 vectorized
__global__ __launch_bounds__(256) void ln_kernel(
        const float* __restrict__ src, const float* __restrict__ ltn,
        const float* __restrict__ gs, const float* __restrict__ bs,
        const float* __restrict__ gl, const float* __restrict__ bl,
        ushort* __restrict__ ctx, ushort* __restrict__ qin) {
    int r = blockIdx.x * 4 + (threadIdx.x >> 6);
    int lane = threadIdx.x & 63;
    int bt = r / N_CTX;
    int i = r - bt * N_CTX;
    const float *x, *g, *b;
    int isl = (i >= N_SRC);
    if (!isl) { x = src + ((size_t)bt * N_SRC + i) * DIMK; g = gs; b = bs; }
    else      { x = ltn + ((size_t)bt * N_LTN + (i - N_SRC)) * DIMK; g = gl; b = bl; }
    float4 v[3]; float s = 0.f, s2 = 0.f;
#pragma unroll
    for (int t = 0; t < 3; t++) {
        float4 xv = *(const float4*)(x + t * 256 + lane * 4);
        v[t] = xv;
        s  += xv.x + xv.y + xv.z + xv.w;
        s2 += xv.x * xv.x + xv.y * xv.y + xv.z * xv.z + xv.w * xv.w;
    }
#pragma unroll
    for (int off = 32; off >= 1; off >>= 1) {
        s  += __shfl_xor(s,  off, 64);
        s2 += __shfl_xor(s2, off, 64);
    }
    float mu  = s * (1.0f / 768.0f);
    float var = s2 * (1.0f / 768.0f) - mu * mu;
    float rs  = rsqrtf(var + 1e-5f);
    ushort* crow = ctx + (size_t)r * DIMK;
    ushort* qrow = isl ? (qin + (size_t)(bt * N_LTN + (i - N_SRC)) * DIMK) : nullptr;
#pragma unroll
    for (int t = 0; t < 3; t++) {
        int idx = t * 256 + lane * 4;
        float4 gv = *(const float4*)(g + idx);
        float4 bv = *(const float4*)(b + idx);
        ushort4 u;
        u.x = f2bf((v[t].x - mu) * rs * gv.x + bv.x);
        u.y = f2bf((v[t].y - mu) * rs * gv.y + bv.y);
        u.z = f2bf((v[t].z - mu) * rs * gv.z + bv.z);
        u.w = f2bf((v[t].w - mu) * rs * gv.w + bv.w);
        *(ushort4*)(crow + idx) = u;
        if (isl) *(ushort4*)(qrow + idx) = u;
    }
}

// ------------------------------- GEMM --------------------------------------
// C[M][N] = A[M][K] @ B[N][K]^T , A/B bf16, acc fp32. (verified R1/R4)
template <typename CT>
__global__ __launch_bounds__(256) void gemm_bt(
        const ushort* __restrict__ A, const ushort* __restrict__ B,
        CT* __restrict__ C, int M, int N, int K) {
    __shared__ ushort lA[128 * 64];
    __shared__ ushort lB[128 * 64];
    int tid = threadIdx.x;
    int lane = tid & 63, wave = tid >> 6;
    int wm = wave >> 1, wn = wave & 1;
    int bn = blockIdx.x, bm = blockIdx.y;

    floatx4 acc[4][4];
#pragma unroll
    for (int mi = 0; mi < 4; mi++)
#pragma unroll
        for (int ni = 0; ni < 4; ni++) acc[mi][ni] = (floatx4){0.f, 0.f, 0.f, 0.f};

    int srow = lane >> 3;
    int schunk = (lane & 7) ^ srow;
    int quad = lane >> 4, lr = lane & 15;
    const int kiters = K >> 6;

    for (int kt = 0; kt < kiters; kt++) {
#pragma unroll
        for (int c2 = 0; c2 < 4; c2++) {
            int row = c2 * 32 + wave * 8 + srow;
            const ushort* gpA = A + ((size_t)(bm * 128 + row) * K + kt * 64 + schunk * 8);
            ushort* lpA = lA + (c2 * 32 + wave * 8) * 64 + lane * 8;
            __builtin_amdgcn_global_load_lds((gvoid*)gpA, (lvoid*)lpA, 16, 0, 0);
            const ushort* gpB = B + ((size_t)(bn * 128 + row) * K + kt * 64 + schunk * 8);
            ushort* lpB = lB + (c2 * 32 + wave * 8) * 64 + lane * 8;
            __builtin_amdgcn_global_load_lds((gvoid*)gpB, (lvoid*)lpB, 16, 0, 0);
        }
        __syncthreads();
#pragma unroll
        for (int ks = 0; ks < 2; ks++) {
            short8 av[4], bv[4];
            int slot = ((ks * 4 + quad) ^ (lane & 7)) * 8;
#pragma unroll
            for (int mi = 0; mi < 4; mi++)
                av[mi] = *(const short8*)(lA + (wm * 64 + mi * 16 + lr) * 64 + slot);
#pragma unroll
            for (int ni = 0; ni < 4; ni++)
                bv[ni] = *(const short8*)(lB + (wn * 64 + ni * 16 + lr) * 64 + slot);
#pragma unroll
            for (int mi = 0; mi < 4; mi++)
#pragma unroll
                for (int ni = 0; ni < 4; ni++)
                    acc[mi][ni] = __builtin_amdgcn_mfma_f32_16x16x32_bf16(
                        av[mi], bv[ni], acc[mi][ni], 0, 0, 0);
        }
        __syncthreads();
    }
#pragma unroll
    for (int mi = 0; mi < 4; mi++)
#pragma unroll
        for (int ni = 0; ni < 4; ni++)
#pragma unroll
            for (int r = 0; r < 4; r++) {
                int row = bm * 128 + wm * 64 + mi * 16 + quad * 4 + r;
                int col = bn * 128 + wn * 64 + ni * 16 + lr;
                float vv = acc[mi][ni][r];
                if constexpr (std::is_same<CT, ushort>::value)
                    C[(size_t)row * N + col] = f2bf(vv);
                else
                    C[(size_t)row * N + col] = vv;
            }
}

// ------------------------- flash attention (split-K) -----------------------
// Wave-local softmax rewrite: wave w owns Q/O rows [w*16, w*16+16).
// Per 128-key tile: S rows for ALL 128 keys live in-wave (8 C-frags), so the
// online-softmax row max/sum are shfl_xor over 16 lanes — no cross-wave LDS
// exchange, no wave-0 serialization. lP is wave-private (same-wave DS ordering
// needs no barrier). Only 2 __syncthreads per tile (K/VT staging).
// PR = row stride for lP/lVT tiles ([64][128] payload): 136 = 128+8 keeps rows
// 272B (17x16B) -> 16B-aligned ds_read_b128, 2-way bank aliasing (free).
#define PR 136

__global__ __launch_bounds__(256) void attn_flash(
        const float* __restrict__ qf, const ushort* __restrict__ kvb,
        float* __restrict__ Op, float* __restrict__ ml) {
    __shared__ ushort lK[128 * 64];
    __shared__ ushort lVT[64 * PR];   // [d 0..63][key 0..127]
    __shared__ ushort lP[64 * PR];    // [qrow 0..63][key 0..127], wave-private rows

    int comb = blockIdx.x, split = blockIdx.y;
    int bt = comb >> 3, h = comb & 7;
    int tid = threadIdx.x;
    int w = tid >> 6, lane = tid & 63, quad = lane >> 4, lr = lane & 15;

    const ushort* kptr = kvb + (size_t)bt * N_CTX * 1024 + h * 64;
    const ushort* vptr = kptr + 512;

    // Q A-frags: A[m=lr][k=kc*32+quad*8+j], q row = w*16+lr
    short8 qa[2];
    {
        const float* p0 = qf + (size_t)(bt * 64 + w * 16 + lr) * DEMB + h * 64;
#pragma unroll
        for (int kc = 0; kc < 2; kc++) {
            const float* p = p0 + kc * 32 + quad * 8;
            float4 f0 = *(const float4*)p;
            float4 f1 = *(const float4*)(p + 4);
            short8 v;
            v[0] = f2bf(f0.x); v[1] = f2bf(f0.y); v[2] = f2bf(f0.z); v[3] = f2bf(f0.w);
            v[4] = f2bf(f1.x); v[5] = f2bf(f1.y); v[6] = f2bf(f1.z); v[7] = f2bf(f1.w);
            qa[kc] = v;
        }
    }

    // O C-frags: accO[nt][r] = O[row=w*16+quad*4+r][col=nt*16+lr]
    floatx4 accO[4];
#pragma unroll
    for (int nt = 0; nt < 4; nt++) accO[nt] = (floatx4){0.f, 0.f, 0.f, 0.f};
    // online-softmax state for rows w*16+quad*4+r (uniform across lr after shfl)
    float m_run[4], l_run[4];
#pragma unroll
    for (int r = 0; r < 4; r++) { m_run[r] = -1e30f; l_run[r] = 0.f; }

    for (int t = split; t < NTILES; t += NSPLIT) {
        int kbase = t * 128;
        __syncthreads();   // prev-iter lK/lVT readers done before restaging

        // ---- stage K (swizzled, 8 lanes/key-row, global_load_lds 16B) ----
#pragma unroll
        for (int c2 = 0; c2 < 4; c2++) {
            int jloc = w * 32 + c2 * 8 + (lane >> 3);
            int chunk = (lane & 7) ^ ((lane >> 3) & 7);
            int jg = kbase + jloc; if (jg > N_CTX - 1) jg = N_CTX - 1;  // clamp tail
            const ushort* gp = kptr + (size_t)jg * 1024 + chunk * 8;
            ushort* lp = lK + (w * 32 + c2 * 8) * 64 + lane * 8;
            __builtin_amdgcn_global_load_lds((gvoid*)gp, (lvoid*)lp, 16, 0, 0);
        }

        // ---- stage V^T via pack-transpose (thread: key-pair x 16 dims) ----
        {
            int k0 = kbase + lane * 2;
            bool valid = (k0 + 1) < N_CTX;   // pairs never straddle (N_CTX even)
            int k0c = valid ? k0 : (N_CTX - 2);
            const ushort* r0 = vptr + (size_t)k0c * 1024 + w * 16;
            const ushort* r1 = r0 + 1024;
            uint4 a0 = *(const uint4*)r0;
            uint4 a1 = *(const uint4*)(r0 + 8);
            uint4 b0 = *(const uint4*)r1;
            uint4 b1 = *(const uint4*)(r1 + 8);
            if (!valid) {
                a0 = make_uint4(0, 0, 0, 0); a1 = a0; b0 = a0; b1 = a0;
            }
            unsigned av8[8] = {a0.x, a0.y, a0.z, a0.w, a1.x, a1.y, a1.z, a1.w};
            unsigned bv8[8] = {b0.x, b0.y, b0.z, b0.w, b1.x, b1.y, b1.z, b1.w};
#pragma unroll
            for (int i = 0; i < 8; i++) {
                unsigned la = av8[i] & 0xffffu, ha = av8[i] >> 16;
                unsigned lb = bv8[i] & 0xffffu, hb = bv8[i] >> 16;
                *(unsigned*)(lVT + (w * 16 + 2 * i) * PR + lane * 2)     = la | (lb << 16);
                *(unsigned*)(lVT + (w * 16 + 2 * i + 1) * PR + lane * 2) = ha | (hb << 16);
            }
        }
        __syncthreads();   // staging complete

        // ---- S = Q @ K^T : wave w computes S[w's 16 rows][all 128 keys] ----
        floatx4 accS[8];
#pragma unroll
        for (int nt = 0; nt < 8; nt++) accS[nt] = (floatx4){0.f, 0.f, 0.f, 0.f};
#pragma unroll
        for (int kc = 0; kc < 2; kc++) {
#pragma unroll
            for (int nt = 0; nt < 8; nt++) {
                int kr = nt * 16 + lr;
                int slot = (kc * 4 + quad) ^ (kr & 7);
                short8 bv = *(const short8*)(lK + kr * 64 + slot * 8);
                accS[nt] = __builtin_amdgcn_mfma_f32_16x16x32_bf16(
                    qa[kc], bv, accS[nt], 0, 0, 0);
            }
        }

        // ---- mask + scale; row max over 128 cols (8 frags + 16-lane shfl) --
        float sc[8][4];
        float tmax[4] = {-1e30f, -1e30f, -1e30f, -1e30f};
#pragma unroll
        for (int nt = 0; nt < 8; nt++) {
            bool vk = (kbase + nt * 16 + lr) < N_CTX;
#pragma unroll
            for (int r = 0; r < 4; r++) {
                float s = vk ? accS[nt][r] * 0.125f : -1e30f;
                sc[nt][r] = s;
                tmax[r] = fmaxf(tmax[r], s);
            }
        }
#pragma unroll
        for (int r = 0; r < 4; r++) {
#pragma unroll
            for (int d = 1; d < 16; d <<= 1) tmax[r] = fmaxf(tmax[r], __shfl_xor(tmax[r], d, 64));
        }
        float alpha[4], lsum[4];
#pragma unroll
        for (int r = 0; r < 4; r++) {
            float mn = fmaxf(m_run[r], tmax[r]);
            alpha[r] = __expf(m_run[r] - mn);
            m_run[r] = mn;
            lsum[r] = 0.f;
        }

        // ---- P = exp(sc - m) -> lP (bf16, wave-private rows); row sums ----
#pragma unroll
        for (int nt = 0; nt < 8; nt++) {
#pragma unroll
            for (int r = 0; r < 4; r++) {
                float p = __expf(sc[nt][r] - m_run[r]);
                lsum[r] += p;
                lP[(w * 16 + quad * 4 + r) * PR + nt * 16 + lr] = f2bf(p);
            }
        }
#pragma unroll
        for (int r = 0; r < 4; r++) {
#pragma unroll
            for (int d = 1; d < 16; d <<= 1) lsum[r] += __shfl_xor(lsum[r], d, 64);
            l_run[r] = l_run[r] * alpha[r] + lsum[r];
        }
        // rescale O (rows quad*4+r match accO reg layout)
#pragma unroll
        for (int nt = 0; nt < 4; nt++) {
            accO[nt][0] *= alpha[0]; accO[nt][1] *= alpha[1];
            accO[nt][2] *= alpha[2]; accO[nt][3] *= alpha[3];
        }

        // ---- O += P @ V^T (wave-local lP read: same-wave DS order, no barrier)
        short8 av[4];
#pragma unroll
        for (int kc = 0; kc < 4; kc++)
            av[kc] = *(const short8*)(lP + (w * 16 + lr) * PR + kc * 32 + quad * 8);
#pragma unroll
        for (int nt = 0; nt < 4; nt++)
#pragma unroll
            for (int kc = 0; kc < 4; kc++) {
                short8 bv = *(const short8*)(lVT + (nt * 16 + lr) * PR + kc * 32 + quad * 8);
                accO[nt] = __builtin_amdgcn_mfma_f32_16x16x32_bf16(av[kc], bv, accO[nt], 0, 0, 0);
            }
    }

    // ---- store partials ----
    float* opb = Op + (size_t)(comb * NSPLIT + split) * 64 * 64;
#pragma unroll
    for (int nt = 0; nt < 4; nt++)
#pragma unroll
        for (int r = 0; r < 4; r++)
            opb[(w * 16 + quad * 4 + r) * 64 + nt * 16 + lr] = accO[nt][r];
    if (lr == 0) {
#pragma unroll
        for (int r = 0; r < 4; r++) {
            int row = w * 16 + quad * 4 + r;
            float* mlp = ml + ((size_t)(comb * NSPLIT + split) * 64 + row) * 2;
            mlp[0] = m_run[r]; mlp[1] = l_run[r];
        }
    }
}

// merge NSPLIT partials per (comb, q): out = sum_s w_s O_s / sum_s w_s l_s
__global__ __launch_bounds__(64) void attn_combine(
        const float* __restrict__ Op, const float* __restrict__ ml,
        ushort* __restrict__ outp) {
    int bx = blockIdx.x;
    int comb = bx >> 6, q = bx & 63;
    int bt = comb >> 3, h = comb & 7;
    int d = threadIdx.x;
    float M = -1e30f;
    for (int s = 0; s < NSPLIT; s++)
        M = fmaxf(M, ml[((size_t)(comb * NSPLIT + s) * 64 + q) * 2]);
    float L = 0.f, O = 0.f;
    for (int s = 0; s < NSPLIT; s++) {
        const float* p = ml + ((size_t)(comb * NSPLIT + s) * 64 + q) * 2;
        float wgt = __expf(p[0] - M);
        L = fmaf(wgt, p[1], L);
        O = fmaf(wgt, Op[((size_t)(comb * NSPLIT + s) * 64 + q) * 64 + d], O);
    }
    outp[(size_t)(bt * 64 + q) * DEMB + h * 64 + d] = f2bf(O / L);
}

// ------------------------------ launcher -----------------------------------
extern "C" void kernel_launch(void* const* d_in, const int* in_sizes, int n_in,
                              void* d_out, int out_size, void* d_ws, size_t ws_size,
                              hipStream_t stream) {
    const float* src   = (const float*)d_in[0];
    const float* ltn   = (const float*)d_in[1];
    const float* g_src = (const float*)d_in[2];
    const float* b_src = (const float*)d_in[3];
    const float* g_ltn = (const float*)d_in[4];
    const float* b_ltn = (const float*)d_in[5];
    const float* Wq    = (const float*)d_in[6];
    const float* Wkv   = (const float*)d_in[7];
    const float* Wo    = (const float*)d_in[8];
    float* out = (float*)d_out;

    char* ws = (char*)d_ws;
    size_t off = 0;
    auto alloc = [&](size_t bytes) -> void* {
        void* p = ws + off;
        off += (bytes + 255) & ~(size_t)255;
        return p;
    };
    ushort* ctx  = (ushort*)alloc((size_t)MROWS * DIMK * 2);   // 101.4 MB
    ushort* qin  = (ushort*)alloc((size_t)512 * DIMK * 2);
    ushort* WkvT = (ushort*)alloc((size_t)1024 * DIMK * 2);
    ushort* WqT  = (ushort*)alloc((size_t)512 * DIMK * 2);
    ushort* WoT  = (ushort*)alloc((size_t)768 * DEMB * 2);
    ushort* kvb  = (ushort*)alloc((size_t)MROWS * 1024 * 2);   // 135.3 MB
    float*  qf   = (float*) alloc((size_t)512 * DEMB * 4);
    ushort* outp = (ushort*)alloc((size_t)512 * DEMB * 2);

    // attention partials alias the ctx buffer (dead after the two GEMMs below)
    float* Op  = (float*)(void*)ctx;                       // 64*16*64*64 f32 = 16.8 MB
    float* mlb = Op + (size_t)64 * NSPLIT * 64 * 64;       // 64*16*64*2 f32

    transpose_all<<<dim3(16, 12, 3), 256, 0, stream>>>(Wkv, Wq, Wo, WkvT, WqT, WoT);

    ln_kernel<<<MROWS / 4, 256, 0, stream>>>(src, ltn, g_src, b_src, g_ltn, b_ltn, ctx, qin);

    gemm_bt<ushort><<<dim3(1024 / 128, MROWS / 128), 256, 0, stream>>>(
        ctx, WkvT, kvb, MROWS, 1024, DIMK);
    gemm_bt<float><<<dim3(512 / 128, 512 / 128), 256, 0, stream>>>(
        qin, WqT, qf, 512, 512, DIMK);

    attn_flash<<<dim3(64, NSPLIT), 256, 0, stream>>>(qf, kvb, Op, mlb);
    attn_combine<<<4096, 64, 0, stream>>>(Op, mlb, outp);

    gemm_bt<float><<<dim3(768 / 128, 512 / 128), 256, 0, stream>>>(
        outp, WoT, out, 512, 768, DEMB);
}